// Round 8
// baseline (474.413 us; speedup 1.0000x reference)
//
#include <hip/hip_runtime.h>

#define LEAKY(x) ((x) >= 0.f ? (x) : 0.01f * (x))

// Problem sizes (fixed): N = M = 1024, F = 144
// Pipeline:
//   GC1: preW=pre@gc1_w, curW=cur@gc1_w, p1=leaky(adj@curW), c1=leaky(adjT@preW)
//   MLP1 (factored): A=p1@fc1_w0+b0, B=c1@fc1_w0; per pair t=leaky(A[i]-B[j]),
//                    h=leaky(t@w1+b1), s=h@w2+b2 -> score1, adj2=s[:,1]
//   GC2 / MLP2: same with gc2_w / fc2_* -> score2, adj_out

// --- two fused small GEMMs: C0 = X0@W (+bias0), C1 = X1@W (+bias1) ---
// X [1024,K], W [K,Cn], block = Cn threads, grid = (1024, 2)
__global__ void k_gemm2(const float* __restrict__ X0, const float* __restrict__ X1,
                        const float* __restrict__ W,
                        const float* __restrict__ bias0, const float* __restrict__ bias1,
                        float* __restrict__ C0, float* __restrict__ C1,
                        int K, int Cn) {
    const float* X    = blockIdx.y ? X1 : X0;
    const float* bias = blockIdx.y ? bias1 : bias0;
    float*       C    = blockIdx.y ? C1 : C0;
    int r = blockIdx.x;
    int c = threadIdx.x;
    float acc = bias ? bias[c] : 0.f;
#pragma unroll 4
    for (int k = 0; k < K; ++k)
        acc = fmaf(X[r * K + k], W[k * Cn + c], acc);  // X row: wave-uniform -> s_load
    C[r * Cn + c] = acc;
}

// --- two fused adj-GEMMs with leaky: Out = leaky(Adj @ Xw) ---
// Adj [1024,1024], Xw [1024,144]; TI rows per block; block = 144 threads
template <int TI>
__global__ void k_adjgemm2(const float* __restrict__ AdjA, const float* __restrict__ XwA,
                           float* __restrict__ OutA,
                           const float* __restrict__ AdjB, const float* __restrict__ XwB,
                           float* __restrict__ OutB) {
    const float* Adj = blockIdx.y ? AdjB : AdjA;
    const float* Xw  = blockIdx.y ? XwB : XwA;
    float*       Out = blockIdx.y ? OutB : OutA;
    int f  = threadIdx.x;          // 0..143
    int i0 = blockIdx.x * TI;
    float acc[TI];
#pragma unroll
    for (int r = 0; r < TI; ++r) acc[r] = 0.f;
#pragma unroll 4
    for (int k = 0; k < 1024; ++k) {
        float w = Xw[k * 144 + f];  // coalesced across f
#pragma unroll
        for (int r = 0; r < TI; ++r)
            acc[r] = fmaf(Adj[(i0 + r) * 1024 + k], w, acc[r]);  // uniform -> s_load
    }
#pragma unroll
    for (int r = 0; r < TI; ++r)
        Out[(i0 + r) * 144 + f] = LEAKY(acc[r]);
}

// --- 1024x1024 transpose, 32x32 LDS tiles ---
__global__ void k_transpose(const float* __restrict__ in, float* __restrict__ out) {
    __shared__ float tile[32][33];
    int bx = blockIdx.x * 32, by = blockIdx.y * 32;
    for (int r = threadIdx.y; r < 32; r += 8)
        tile[r][threadIdx.x] = in[(by + r) * 1024 + bx + threadIdx.x];
    __syncthreads();
    for (int r = threadIdx.y; r < 32; r += 8)
        out[(bx + r) * 1024 + by + threadIdx.x] = tile[threadIdx.x][r];
}

// --- per-pair MLP (layer0 pre-factored into A,B; b0 folded into A) ---
// A,B [1024,72]; w1 [72,36]; w2 [36,2]; 16x16 pair tile per block (256 thr)
__global__ __launch_bounds__(256) void k_pair_mlp(
    const float* __restrict__ A, const float* __restrict__ B,
    const float* __restrict__ w1, const float* __restrict__ b1,
    const float* __restrict__ w2, const float* __restrict__ b2,
    float2* __restrict__ score, float* __restrict__ adjn) {
    __shared__ float Ash[16][76];   // stride 76: rows 16B-aligned, 2-way banks (free)
    __shared__ float Bsh[16][76];
    __shared__ float w1sh[72 * 36];
    int t  = threadIdx.x;
    int tx = t & 15, ty = t >> 4;
    int i0 = blockIdx.y * 16, j0 = blockIdx.x * 16;

    for (int idx = t; idx < 16 * 72; idx += 256) {
        int r = idx / 72, c = idx - r * 72;
        Ash[r][c] = A[(i0 + r) * 72 + c];
        Bsh[r][c] = B[(j0 + r) * 72 + c];
    }
    for (int idx = t; idx < 72 * 36; idx += 256) w1sh[idx] = w1[idx];
    __syncthreads();

    float h[36];
#pragma unroll
    for (int m = 0; m < 36; ++m) h[m] = b1[m];

#pragma unroll 4
    for (int k = 0; k < 72; ++k) {
        float tk = Ash[ty][k] - Bsh[tx][k];
        tk = LEAKY(tk);
#pragma unroll
        for (int m = 0; m < 36; ++m)
            h[m] = fmaf(tk, w1sh[k * 36 + m], h[m]);
    }

    float s0 = b2[0], s1 = b2[1];
#pragma unroll
    for (int m = 0; m < 36; ++m) {
        float hm = LEAKY(h[m]);
        s0 = fmaf(hm, w2[m * 2 + 0], s0);
        s1 = fmaf(hm, w2[m * 2 + 1], s1);
    }
    int i = i0 + ty, j = j0 + tx;
    score[i * 1024 + j] = make_float2(s0, s1);  // coalesced float2
    adjn[i * 1024 + j]  = s1;
}

extern "C" void kernel_launch(void* const* d_in, const int* in_sizes, int n_in,
                              void* d_out, int out_size, void* d_ws, size_t ws_size,
                              hipStream_t stream) {
    const float* pre    = (const float*)d_in[0];
    const float* cur    = (const float*)d_in[1];
    const float* adj    = (const float*)d_in[2];
    const float* gc1_w  = (const float*)d_in[3];
    const float* gc2_w  = (const float*)d_in[4];
    const float* fc1_w0 = (const float*)d_in[5];
    const float* fc1_b0 = (const float*)d_in[6];
    const float* fc1_w1 = (const float*)d_in[7];
    const float* fc1_b1 = (const float*)d_in[8];
    const float* fc1_w2 = (const float*)d_in[9];
    const float* fc1_b2 = (const float*)d_in[10];
    const float* fc2_w0 = (const float*)d_in[11];
    const float* fc2_b0 = (const float*)d_in[12];
    const float* fc2_w1 = (const float*)d_in[13];
    const float* fc2_b1 = (const float*)d_in[14];
    const float* fc2_w2 = (const float*)d_in[15];
    const float* fc2_b2 = (const float*)d_in[16];

    // workspace layout (floats): total ~11.3 MB
    float* ws   = (float*)d_ws;
    float* preW = ws;                   // 1024*144
    float* curW = preW + 147456;        // 1024*144
    float* p1   = curW + 147456;        // 1024*144
    float* c1   = p1 + 147456;          // 1024*144
    float* Abuf = c1 + 147456;          // 1024*72
    float* Bbuf = Abuf + 73728;         // 1024*72
    float* adjT = Bbuf + 73728;         // 1024*1024 (reused for both transposes)
    float* adj2 = adjT + 1048576;       // 1024*1024

    float* score1 = (float*)d_out;                 // [1M,2]
    float* score2 = score1 + 2 * 1048576;          // [1M,2]
    float* adjout = score2 + 2 * 1048576;          // [1M]

    // --- GC1 ---
    k_gemm2<<<dim3(1024, 2), 144, 0, stream>>>(pre, cur, gc1_w, nullptr, nullptr,
                                               preW, curW, 144, 144);
    k_transpose<<<dim3(32, 32), dim3(32, 8), 0, stream>>>(adj, adjT);
    k_adjgemm2<4><<<dim3(256, 2), 144, 0, stream>>>(adj, curW, p1, adjT, preW, c1);

    // --- MLP1 ---
    k_gemm2<<<dim3(1024, 2), 72, 0, stream>>>(p1, c1, fc1_w0, fc1_b0, nullptr,
                                              Abuf, Bbuf, 144, 72);
    k_pair_mlp<<<dim3(64, 64), 256, 0, stream>>>(Abuf, Bbuf, fc1_w1, fc1_b1, fc1_w2,
                                                 fc1_b2, (float2*)score1, adj2);

    // --- GC2 (reuse preW/curW) ---
    k_gemm2<<<dim3(1024, 2), 144, 0, stream>>>(p1, c1, gc2_w, nullptr, nullptr,
                                               preW, curW, 144, 144);
    k_transpose<<<dim3(32, 32), dim3(32, 8), 0, stream>>>(adj2, adjT);
    k_adjgemm2<4><<<dim3(256, 2), 144, 0, stream>>>(adj2, curW, p1, adjT, preW, c1);

    // --- MLP2 ---
    k_gemm2<<<dim3(1024, 2), 72, 0, stream>>>(p1, c1, fc2_w0, fc2_b0, nullptr,
                                              Abuf, Bbuf, 144, 72);
    k_pair_mlp<<<dim3(64, 64), 256, 0, stream>>>(Abuf, Bbuf, fc2_w1, fc2_b1, fc2_w2,
                                                 fc2_b2, (float2*)score2, adjout);
}

// Round 12
// 401.347 us; speedup vs baseline: 1.1821x; 1.1821x over previous
//
#include <hip/hip_runtime.h>

#define LEAKY(x) ((x) >= 0.f ? (x) : 0.01f * (x))

typedef float f32x4 __attribute__((ext_vector_type(4)));
typedef __bf16 bf16x8 __attribute__((ext_vector_type(8)));

// Problem sizes (fixed): N = M = 1024, F = 144
// Pipeline:
//   GC1: preW=pre@gc1_w, curW=cur@gc1_w, p1=leaky(adj@curW), c1=leaky(adjT@preW)
//   MLP1 (factored): A=p1@fc1_w0+b0, B=c1@fc1_w0; per pair t=leaky(A[i]-B[j]),
//                    h=leaky(t@w1+b1), s=h@w2+b2 -> score1, adj2=s[:,1]
//   GC2 / MLP2: same with gc2_w / fc2_* -> score2, adj_out

// --- two fused small GEMMs: C0 = X0@W (+bias0), C1 = X1@W (+bias1) ---
__global__ void k_gemm2(const float* __restrict__ X0, const float* __restrict__ X1,
                        const float* __restrict__ W,
                        const float* __restrict__ bias0, const float* __restrict__ bias1,
                        float* __restrict__ C0, float* __restrict__ C1,
                        int K, int Cn) {
    const float* X    = blockIdx.y ? X1 : X0;
    const float* bias = blockIdx.y ? bias1 : bias0;
    float*       C    = blockIdx.y ? C1 : C0;
    int r = blockIdx.x;
    int c = threadIdx.x;
    float acc = bias ? bias[c] : 0.f;
#pragma unroll 4
    for (int k = 0; k < K; ++k)
        acc = fmaf(X[r * K + k], W[k * Cn + c], acc);
    C[r * Cn + c] = acc;
}

// --- two fused adj-GEMMs with leaky: Out = leaky(Adj @ Xw) ---
template <int TI>
__global__ void k_adjgemm2(const float* __restrict__ AdjA, const float* __restrict__ XwA,
                           float* __restrict__ OutA,
                           const float* __restrict__ AdjB, const float* __restrict__ XwB,
                           float* __restrict__ OutB) {
    const float* Adj = blockIdx.y ? AdjB : AdjA;
    const float* Xw  = blockIdx.y ? XwB : XwA;
    float*       Out = blockIdx.y ? OutB : OutA;
    int f  = threadIdx.x;          // 0..143
    int i0 = blockIdx.x * TI;
    float acc[TI];
#pragma unroll
    for (int r = 0; r < TI; ++r) acc[r] = 0.f;
#pragma unroll 4
    for (int k = 0; k < 1024; ++k) {
        float w = Xw[k * 144 + f];
#pragma unroll
        for (int r = 0; r < TI; ++r)
            acc[r] = fmaf(Adj[(i0 + r) * 1024 + k], w, acc[r]);
    }
#pragma unroll
    for (int r = 0; r < TI; ++r)
        Out[(i0 + r) * 144 + f] = LEAKY(acc[r]);
}

// --- 1024x1024 transpose, 32x32 LDS tiles ---
__global__ void k_transpose(const float* __restrict__ in, float* __restrict__ out) {
    __shared__ float tile[32][33];
    int bx = blockIdx.x * 32, by = blockIdx.y * 32;
    for (int r = threadIdx.y; r < 32; r += 8)
        tile[r][threadIdx.x] = in[(by + r) * 1024 + bx + threadIdx.x];
    __syncthreads();
    for (int r = threadIdx.y; r < 32; r += 8)
        out[(bx + r) * 1024 + by + threadIdx.x] = tile[threadIdx.x][r];
}

// --- per-pair MLP via MFMA ---
// GEMM orientation: M = hidden (36 pad 48), N = pairs (16), K = 72 (pad 96).
// A-operand = W1^T (lane: row m = mt*16+lc, k = ks*32+g*8+b)
// B-operand = T^T  (lane: col pair = lc,    k = ks*32+g*8+b), t = leaky(A[i]-B[j])
// C (m89-verified): col(pair) = lane&15, row(m) = (lane>>4)*4+q
// k-mapping errors cancel (same assumed pi on both operands).
__global__ __launch_bounds__(256) void k_pair_mlp_mfma(
    const float* __restrict__ A, const float* __restrict__ B,
    const float* __restrict__ w1, const float* __restrict__ b1,
    const float* __restrict__ w2, const float* __restrict__ b2,
    float2* __restrict__ score, float* __restrict__ adjn)
{
    __shared__ float Ash[16][104];  // 104: 16B-aligned rows, stride 26 banks (coprime-ish)
    __shared__ float Bsh[16][104];

    const int t  = threadIdx.x;
    const int i0 = blockIdx.y * 16, j0 = blockIdx.x * 16;

    // stage A,B tiles [16][72] (float4), zero-pad cols 72..95
    for (int idx = t; idx < 288; idx += 256) {
        int r = idx / 18, c = (idx - r * 18) * 4;
        *(float4*)&Ash[r][c] = *(const float4*)&A[(i0 + r) * 72 + c];
        *(float4*)&Bsh[r][c] = *(const float4*)&B[(j0 + r) * 72 + c];
    }
    for (int idx = t; idx < 16 * 24; idx += 256) {
        int r = idx / 24, c = 72 + (idx - r * 24);
        Ash[r][c] = 0.f; Bsh[r][c] = 0.f;
    }
    __syncthreads();

    const int lane = t & 63;
    const int wv   = t >> 6;      // wave id: handles i-rows di = 4*wv .. 4*wv+3
    const int lc   = lane & 15;
    const int g    = lane >> 4;

    // W1^T fragments (from global; w1 is 10KB -> L1-resident)
    bf16x8 w1f[3][3];
#pragma unroll
    for (int ks = 0; ks < 3; ++ks)
#pragma unroll
        for (int mt = 0; mt < 3; ++mt) {
            bf16x8 f;
            int mm = mt * 16 + lc;
#pragma unroll
            for (int b = 0; b < 8; ++b) {
                int kk = ks * 32 + g * 8 + b;
                float v = (kk < 72 && mm < 36) ? w1[kk * 36 + mm] : 0.f;
                f[b] = (__bf16)v;
            }
            w1f[ks][mt] = f;
        }

    // per-lane b1/w2 values for m = mt*16 + g*4 + q (zero-padded m>=36)
    float b1v[3][4], w20[3][4], w21[3][4];
#pragma unroll
    for (int mt = 0; mt < 3; ++mt)
#pragma unroll
        for (int q = 0; q < 4; ++q) {
            int m = mt * 16 + g * 4 + q;
            bool ok = m < 36;
            b1v[mt][q] = ok ? b1[m] : 0.f;
            w20[mt][q] = ok ? w2[m * 2 + 0] : 0.f;
            w21[mt][q] = ok ? w2[m * 2 + 1] : 0.f;
        }
    const float bb0 = b2[0], bb1 = b2[1];

    // hoist B-row (pair = lc) k-slices: reused across all 4 di
    float4 Bv[3][2];
#pragma unroll
    for (int ks = 0; ks < 3; ++ks) {
        Bv[ks][0] = *(const float4*)&Bsh[lc][ks * 32 + g * 8];
        Bv[ks][1] = *(const float4*)&Bsh[lc][ks * 32 + g * 8 + 4];
    }

#pragma unroll
    for (int ps = 0; ps < 4; ++ps) {
        const int di = wv * 4 + ps;
        f32x4 acc[3];
#pragma unroll
        for (int mt = 0; mt < 3; ++mt)
            acc[mt] = (f32x4){b1v[mt][0], b1v[mt][1], b1v[mt][2], b1v[mt][3]};

#pragma unroll
        for (int ks = 0; ks < 3; ++ks) {
            float4 Av0 = *(const float4*)&Ash[di][ks * 32 + g * 8];      // broadcast
            float4 Av1 = *(const float4*)&Ash[di][ks * 32 + g * 8 + 4];
            bf16x8 tf;
            float d;
            d = Av0.x - Bv[ks][0].x; tf[0] = (__bf16)(d >= 0.f ? d : 0.01f * d);
            d = Av0.y - Bv[ks][0].y; tf[1] = (__bf16)(d >= 0.f ? d : 0.01f * d);
            d = Av0.z - Bv[ks][0].z; tf[2] = (__bf16)(d >= 0.f ? d : 0.01f * d);
            d = Av0.w - Bv[ks][0].w; tf[3] = (__bf16)(d >= 0.f ? d : 0.01f * d);
            d = Av1.x - Bv[ks][1].x; tf[4] = (__bf16)(d >= 0.f ? d : 0.01f * d);
            d = Av1.y - Bv[ks][1].y; tf[5] = (__bf16)(d >= 0.f ? d : 0.01f * d);
            d = Av1.z - Bv[ks][1].z; tf[6] = (__bf16)(d >= 0.f ? d : 0.01f * d);
            d = Av1.w - Bv[ks][1].w; tf[7] = (__bf16)(d >= 0.f ? d : 0.01f * d);
#pragma unroll
            for (int mt = 0; mt < 3; ++mt)
                acc[mt] = __builtin_amdgcn_mfma_f32_16x16x32_bf16(
                    w1f[ks][mt], tf, acc[mt], 0, 0, 0);
        }

        // layer 2: s = leaky(h) @ w2 + b2 ; per-lane partial over its 12 m's,
        // then sum over the 4 quarters (lanes differing in bits 4..5)
        float s0 = 0.f, s1 = 0.f;
#pragma unroll
        for (int mt = 0; mt < 3; ++mt)
#pragma unroll
            for (int q = 0; q < 4; ++q) {
                float h = acc[mt][q];
                h = h >= 0.f ? h : 0.01f * h;
                s0 = fmaf(h, w20[mt][q], s0);
                s1 = fmaf(h, w21[mt][q], s1);
            }
        s0 += __shfl_xor(s0, 16); s1 += __shfl_xor(s1, 16);
        s0 += __shfl_xor(s0, 32); s1 += __shfl_xor(s1, 32);

        if (lane < 16) {
            int i = i0 + di, j = j0 + lc;
            float r0 = s0 + bb0, r1 = s1 + bb1;
            score[i * 1024 + j] = make_float2(r0, r1);   // coalesced 128B
            adjn[i * 1024 + j]  = r1;
        }
    }
}

extern "C" void kernel_launch(void* const* d_in, const int* in_sizes, int n_in,
                              void* d_out, int out_size, void* d_ws, size_t ws_size,
                              hipStream_t stream) {
    const float* pre    = (const float*)d_in[0];
    const float* cur    = (const float*)d_in[1];
    const float* adj    = (const float*)d_in[2];
    const float* gc1_w  = (const float*)d_in[3];
    const float* gc2_w  = (const float*)d_in[4];
    const float* fc1_w0 = (const float*)d_in[5];
    const float* fc1_b0 = (const float*)d_in[6];
    const float* fc1_w1 = (const float*)d_in[7];
    const float* fc1_b1 = (const float*)d_in[8];
    const float* fc1_w2 = (const float*)d_in[9];
    const float* fc1_b2 = (const float*)d_in[10];
    const float* fc2_w0 = (const float*)d_in[11];
    const float* fc2_b0 = (const float*)d_in[12];
    const float* fc2_w1 = (const float*)d_in[13];
    const float* fc2_b1 = (const float*)d_in[14];
    const float* fc2_w2 = (const float*)d_in[15];
    const float* fc2_b2 = (const float*)d_in[16];

    // workspace layout (floats): total ~11.3 MB
    float* ws   = (float*)d_ws;
    float* preW = ws;                   // 1024*144
    float* curW = preW + 147456;
    float* p1   = curW + 147456;
    float* c1   = p1 + 147456;
    float* Abuf = c1 + 147456;          // 1024*72
    float* Bbuf = Abuf + 73728;
    float* adjT = Bbuf + 73728;         // 1024*1024
    float* adj2 = adjT + 1048576;       // 1024*1024

    float* score1 = (float*)d_out;                 // [1M,2]
    float* score2 = score1 + 2 * 1048576;          // [1M,2]
    float* adjout = score2 + 2 * 1048576;          // [1M]

    // --- GC1 ---
    k_gemm2<<<dim3(1024, 2), 144, 0, stream>>>(pre, cur, gc1_w, nullptr, nullptr,
                                               preW, curW, 144, 144);
    k_transpose<<<dim3(32, 32), dim3(32, 8), 0, stream>>>(adj, adjT);
    k_adjgemm2<4><<<dim3(256, 2), 144, 0, stream>>>(adj, curW, p1, adjT, preW, c1);

    // --- MLP1 ---
    k_gemm2<<<dim3(1024, 2), 72, 0, stream>>>(p1, c1, fc1_w0, fc1_b0, nullptr,
                                              Abuf, Bbuf, 144, 72);
    k_pair_mlp_mfma<<<dim3(64, 64), 256, 0, stream>>>(Abuf, Bbuf, fc1_w1, fc1_b1,
                                                      fc1_w2, fc1_b2,
                                                      (float2*)score1, adj2);

    // --- GC2 (reuse preW/curW) ---
    k_gemm2<<<dim3(1024, 2), 144, 0, stream>>>(p1, c1, gc2_w, nullptr, nullptr,
                                               preW, curW, 144, 144);
    k_transpose<<<dim3(32, 32), dim3(32, 8), 0, stream>>>(adj2, adjT);
    k_adjgemm2<4><<<dim3(256, 2), 144, 0, stream>>>(adj2, curW, p1, adjT, preW, c1);

    // --- MLP2 ---
    k_gemm2<<<dim3(1024, 2), 72, 0, stream>>>(p1, c1, fc2_w0, fc2_b0, nullptr,
                                              Abuf, Bbuf, 144, 72);
    k_pair_mlp_mfma<<<dim3(64, 64), 256, 0, stream>>>(Abuf, Bbuf, fc2_w1, fc2_b1,
                                                      fc2_w2, fc2_b2,
                                                      (float2*)score2, adjout);
}

// Round 13
// 278.818 us; speedup vs baseline: 1.7015x; 1.4395x over previous
//
#include <hip/hip_runtime.h>

typedef float f32x4 __attribute__((ext_vector_type(4)));
typedef __bf16 bf16x8 __attribute__((ext_vector_type(8)));

// N = M = 1024, F = 144. Pipeline:
//   GC: XwT = (X@W)^T bf16;  p = leaky(adj@Xw) via MFMA;  c = leaky(adjT@Xw')
//   MLP (factored): A=p@w0+b0, B=c@w0; t=leaky(A[i]-B[j]); h=leaky(t@w1+b1); s=h@w2+b2

// --- fp32 small GEMM for MLP prep: C0 = X0@W + b0, C1 = X1@W ---
__global__ void k_gemm2(const float* __restrict__ X0, const float* __restrict__ X1,
                        const float* __restrict__ W,
                        const float* __restrict__ bias0, const float* __restrict__ bias1,
                        float* __restrict__ C0, float* __restrict__ C1,
                        int K, int Cn) {
    const float* X    = blockIdx.y ? X1 : X0;
    const float* bias = blockIdx.y ? bias1 : bias0;
    float*       C    = blockIdx.y ? C1 : C0;
    int r = blockIdx.x;
    int c = threadIdx.x;
    float acc = bias ? bias[c] : 0.f;
#pragma unroll 4
    for (int k = 0; k < K; ++k)
        acc = fmaf(X[r * K + k], W[k * Cn + c], acc);
    C[r * Cn + c] = acc;
}

// --- GC prep GEMM: OutT = (X@W)^T in bf16, [144][1024]. K=Cn=144 fixed ---
__global__ void k_gemm2bt(const float* __restrict__ X0, const float* __restrict__ X1,
                          const float* __restrict__ W,
                          __bf16* __restrict__ OutT0, __bf16* __restrict__ OutT1) {
    const float* X  = blockIdx.y ? X1 : X0;
    __bf16* OutT    = blockIdx.y ? OutT1 : OutT0;
    int r = blockIdx.x;
    int c = threadIdx.x;   // 0..143
    float acc = 0.f;
#pragma unroll 4
    for (int k = 0; k < 144; ++k)
        acc = fmaf(X[r * 144 + k], W[k * 144 + c], acc);
    OutT[c * 1024 + r] = (__bf16)acc;
}

// --- 1024x1024 fp32 transpose, 32x32 LDS tiles ---
__global__ void k_transpose(const float* __restrict__ in, float* __restrict__ out) {
    __shared__ float tile[32][33];
    int bx = blockIdx.x * 32, by = blockIdx.y * 32;
    for (int r = threadIdx.y; r < 32; r += 8)
        tile[r][threadIdx.x] = in[(by + r) * 1024 + bx + threadIdx.x];
    __syncthreads();
    for (int r = threadIdx.y; r < 32; r += 8)
        out[(bx + r) * 1024 + by + threadIdx.x] = tile[threadIdx.x][r];
}

// --- adj GEMM via MFMA: Out[i][f] = leaky( sum_k Brow[i][k] * XwT[f][k] ) ---
// Orientation: A-operand = XwT (m=f), B-operand = adj rows (n=i), k inner.
// Block = 192 thr = 3 waves; wave wv covers f-frags mt = 3*wv..3*wv+2.
// Fragment layout identical to the HW-validated pair_mlp kernel.
__global__ __launch_bounds__(192) void k_adjmm(
    const float* __restrict__ Brow0, const __bf16* __restrict__ AwT0, float* __restrict__ Out0,
    const float* __restrict__ Brow1, const __bf16* __restrict__ AwT1, float* __restrict__ Out1)
{
    const float*  Brow = blockIdx.y ? Brow1 : Brow0;
    const __bf16* AwT  = blockIdx.y ? AwT1 : AwT0;
    float*        Out  = blockIdx.y ? Out1 : Out0;

    const int lane = threadIdx.x & 63;
    const int wv   = threadIdx.x >> 6;       // 0..2
    const int lc   = lane & 15, g = lane >> 4;
    const int i0   = blockIdx.x * 16;
    const int mtb  = wv * 3;

    const float* bp = Brow + (size_t)(i0 + lc) * 1024 + g * 8;

    f32x4 acc[3];
#pragma unroll
    for (int m = 0; m < 3; ++m) acc[m] = (f32x4){0.f, 0.f, 0.f, 0.f};

#pragma unroll 4
    for (int k0 = 0; k0 < 1024; k0 += 32) {
        float4 b0 = *(const float4*)(bp + k0);
        float4 b1 = *(const float4*)(bp + k0 + 4);
        bf16x8 bf;
        bf[0] = (__bf16)b0.x; bf[1] = (__bf16)b0.y; bf[2] = (__bf16)b0.z; bf[3] = (__bf16)b0.w;
        bf[4] = (__bf16)b1.x; bf[5] = (__bf16)b1.y; bf[6] = (__bf16)b1.z; bf[7] = (__bf16)b1.w;
#pragma unroll
        for (int m = 0; m < 3; ++m) {
            bf16x8 af = *(const bf16x8*)(AwT + (size_t)((mtb + m) * 16 + lc) * 1024 + k0 + g * 8);
            acc[m] = __builtin_amdgcn_mfma_f32_16x16x32_bf16(af, bf, acc[m], 0, 0, 0);
        }
    }

    // C: col(i) = lane&15, row(f) = (lane>>4)*4 + q  [HW-validated mapping]
#pragma unroll
    for (int m = 0; m < 3; ++m) {
        float4 v;
        v.x = fmaxf(acc[m][0], 0.01f * acc[m][0]);
        v.y = fmaxf(acc[m][1], 0.01f * acc[m][1]);
        v.z = fmaxf(acc[m][2], 0.01f * acc[m][2]);
        v.w = fmaxf(acc[m][3], 0.01f * acc[m][3]);
        *(float4*)&Out[(size_t)(i0 + lc) * 144 + (mtb + m) * 16 + g * 4] = v;
    }
}

// --- build W1^T MFMA fragments once: out[(fc*9 + ks*3+mt)*64 + lane] ---
// b1 folded in at k==72 (consumed via constant-1 channel in pair_mlp).
__global__ void k_prep_w1(const float* __restrict__ w1a, const float* __restrict__ b1a,
                          const float* __restrict__ w1b, const float* __restrict__ b1b,
                          bf16x8* __restrict__ out) {
    int l  = threadIdx.x;          // 64
    int fc = blockIdx.x;           // 0,1
    const float* w1 = fc ? w1b : w1a;
    const float* b1 = fc ? b1b : b1a;
    int lc = l & 15, g = l >> 4;
    for (int ks = 0; ks < 3; ++ks)
        for (int mt = 0; mt < 3; ++mt) {
            bf16x8 f;
            int mm = mt * 16 + lc;
#pragma unroll
            for (int b = 0; b < 8; ++b) {
                int kk = ks * 32 + g * 8 + b;
                float v = 0.f;
                if (mm < 36) {
                    if (kk < 72)       v = w1[kk * 36 + mm];
                    else if (kk == 72) v = b1[mm];
                }
                f[b] = (__bf16)v;
            }
            out[(fc * 9 + ks * 3 + mt) * 64 + l] = f;
        }
}

// --- per-pair MLP via MFMA (v2: precomputed w1 frags, b1 via k=72 channel) ---
// M = hidden (36 pad 48), N = pairs (16), K = 72 (+1 bias ch, pad 96).
__global__ __launch_bounds__(256) void k_pair_mlp_mfma(
    const float* __restrict__ A, const float* __restrict__ B,
    const bf16x8* __restrict__ w1fp,
    const float* __restrict__ w2, const float* __restrict__ b2,
    float2* __restrict__ score, float* __restrict__ adjn)
{
    __shared__ float Ash[16][104];
    __shared__ float Bsh[16][104];

    const int t  = threadIdx.x;
    const int i0 = blockIdx.y * 16, j0 = blockIdx.x * 16;

    for (int idx = t; idx < 288; idx += 256) {
        int r = idx / 18, c = (idx - r * 18) * 4;
        *(float4*)&Ash[r][c] = *(const float4*)&A[(i0 + r) * 72 + c];
        *(float4*)&Bsh[r][c] = *(const float4*)&B[(j0 + r) * 72 + c];
    }
    for (int idx = t; idx < 16 * 24; idx += 256) {
        int r = idx / 24, c = 72 + (idx - r * 24);
        Ash[r][c] = (c == 72) ? 1.0f : 0.f;   // bias channel
        Bsh[r][c] = 0.f;
    }
    __syncthreads();

    const int lane = t & 63;
    const int wv   = t >> 6;
    const int lc   = lane & 15;
    const int g    = lane >> 4;

    // precomputed W1^T fragments: 9 coalesced 16B loads
    bf16x8 w1f[3][3];
#pragma unroll
    for (int ks = 0; ks < 3; ++ks)
#pragma unroll
        for (int mt = 0; mt < 3; ++mt)
            w1f[ks][mt] = w1fp[(ks * 3 + mt) * 64 + lane];

    // per-lane w2 values for m = mt*16 + g*4 + q
    float w20[3][4], w21[3][4];
#pragma unroll
    for (int mt = 0; mt < 3; ++mt)
#pragma unroll
        for (int q = 0; q < 4; ++q) {
            int m = mt * 16 + g * 4 + q;
            bool ok = m < 36;
            w20[mt][q] = ok ? w2[m * 2 + 0] : 0.f;
            w21[mt][q] = ok ? w2[m * 2 + 1] : 0.f;
        }
    const float bb0 = b2[0], bb1 = b2[1];

    float4 Bv[3][2];
#pragma unroll
    for (int ks = 0; ks < 3; ++ks) {
        Bv[ks][0] = *(const float4*)&Bsh[lc][ks * 32 + g * 8];
        Bv[ks][1] = *(const float4*)&Bsh[lc][ks * 32 + g * 8 + 4];
    }

#pragma unroll
    for (int ps = 0; ps < 4; ++ps) {
        const int di = wv * 4 + ps;
        f32x4 acc[3];
#pragma unroll
        for (int mt = 0; mt < 3; ++mt) acc[mt] = (f32x4){0.f, 0.f, 0.f, 0.f};

#pragma unroll
        for (int ks = 0; ks < 3; ++ks) {
            float4 Av0 = *(const float4*)&Ash[di][ks * 32 + g * 8];
            float4 Av1 = *(const float4*)&Ash[di][ks * 32 + g * 8 + 4];
            bf16x8 tf;
            float d;
            d = Av0.x - Bv[ks][0].x; tf[0] = (__bf16)fmaxf(d, 0.01f * d);
            d = Av0.y - Bv[ks][0].y; tf[1] = (__bf16)fmaxf(d, 0.01f * d);
            d = Av0.z - Bv[ks][0].z; tf[2] = (__bf16)fmaxf(d, 0.01f * d);
            d = Av0.w - Bv[ks][0].w; tf[3] = (__bf16)fmaxf(d, 0.01f * d);
            d = Av1.x - Bv[ks][1].x; tf[4] = (__bf16)fmaxf(d, 0.01f * d);
            d = Av1.y - Bv[ks][1].y; tf[5] = (__bf16)fmaxf(d, 0.01f * d);
            d = Av1.z - Bv[ks][1].z; tf[6] = (__bf16)fmaxf(d, 0.01f * d);
            d = Av1.w - Bv[ks][1].w; tf[7] = (__bf16)fmaxf(d, 0.01f * d);
#pragma unroll
            for (int mt = 0; mt < 3; ++mt)
                acc[mt] = __builtin_amdgcn_mfma_f32_16x16x32_bf16(
                    w1f[ks][mt], tf, acc[mt], 0, 0, 0);
        }

        float s0 = 0.f, s1 = 0.f;
#pragma unroll
        for (int mt = 0; mt < 3; ++mt)
#pragma unroll
            for (int q = 0; q < 4; ++q) {
                float h = acc[mt][q];
                h = fmaxf(h, 0.01f * h);
                s0 = fmaf(h, w20[mt][q], s0);
                s1 = fmaf(h, w21[mt][q], s1);
            }
        s0 += __shfl_xor(s0, 16); s1 += __shfl_xor(s1, 16);
        s0 += __shfl_xor(s0, 32); s1 += __shfl_xor(s1, 32);

        if (lane < 16) {
            int i = i0 + di, j = j0 + lc;
            float r0 = s0 + bb0, r1 = s1 + bb1;
            score[i * 1024 + j] = make_float2(r0, r1);
            adjn[i * 1024 + j]  = r1;
        }
    }
}

extern "C" void kernel_launch(void* const* d_in, const int* in_sizes, int n_in,
                              void* d_out, int out_size, void* d_ws, size_t ws_size,
                              hipStream_t stream) {
    const float* pre    = (const float*)d_in[0];
    const float* cur    = (const float*)d_in[1];
    const float* adj    = (const float*)d_in[2];
    const float* gc1_w  = (const float*)d_in[3];
    const float* gc2_w  = (const float*)d_in[4];
    const float* fc1_w0 = (const float*)d_in[5];
    const float* fc1_b0 = (const float*)d_in[6];
    const float* fc1_w1 = (const float*)d_in[7];
    const float* fc1_b1 = (const float*)d_in[8];
    const float* fc1_w2 = (const float*)d_in[9];
    const float* fc1_b2 = (const float*)d_in[10];
    const float* fc2_w0 = (const float*)d_in[11];
    const float* fc2_b0 = (const float*)d_in[12];
    const float* fc2_w1 = (const float*)d_in[13];
    const float* fc2_b1 = (const float*)d_in[14];
    const float* fc2_w2 = (const float*)d_in[15];
    const float* fc2_b2 = (const float*)d_in[16];

    // workspace layout (~10.5 MB)
    float*  ws    = (float*)d_ws;
    float*  p1    = ws;                        // 1024*144
    float*  c1    = p1 + 147456;               // 1024*144
    float*  Abuf  = c1 + 147456;               // 1024*72
    float*  Bbuf  = Abuf + 73728;              // 1024*72
    float*  adjT  = Bbuf + 73728;              // 1024*1024
    float*  adj2  = adjT + 1048576;            // 1024*1024
    __bf16* preWT = (__bf16*)(adj2 + 1048576); // 144*1024 bf16
    __bf16* curWT = preWT + 147456;            // 144*1024 bf16
    bf16x8* w1fb  = (bf16x8*)(curWT + 147456); // 2*9*64 frags

    float* score1 = (float*)d_out;             // [1M,2]
    float* score2 = score1 + 2 * 1048576;      // [1M,2]
    float* adjout = score2 + 2 * 1048576;      // [1M]

    k_prep_w1<<<2, 64, 0, stream>>>(fc1_w1, fc1_b1, fc2_w1, fc2_b1, w1fb);

    // --- GC1: preWT = (pre@gc1_w)^T bf16, curWT = (cur@gc1_w)^T bf16 ---
    k_gemm2bt<<<dim3(1024, 2), 144, 0, stream>>>(pre, cur, gc1_w, preWT, curWT);
    k_transpose<<<dim3(32, 32), dim3(32, 8), 0, stream>>>(adj, adjT);
    // p1 = leaky(adj@curW), c1 = leaky(adjT@preW)
    k_adjmm<<<dim3(64, 2), 192, 0, stream>>>(adj, curWT, p1, adjT, preWT, c1);

    // --- MLP1 ---
    k_gemm2<<<dim3(1024, 2), 72, 0, stream>>>(p1, c1, fc1_w0, fc1_b0, nullptr,
                                              Abuf, Bbuf, 144, 72);
    k_pair_mlp_mfma<<<dim3(64, 64), 256, 0, stream>>>(Abuf, Bbuf, w1fb,
                                                      fc1_w2, fc1_b2,
                                                      (float2*)score1, adj2);

    // --- GC2 ---
    k_gemm2bt<<<dim3(1024, 2), 144, 0, stream>>>(p1, c1, gc2_w, preWT, curWT);
    k_transpose<<<dim3(32, 32), dim3(32, 8), 0, stream>>>(adj2, adjT);
    k_adjmm<<<dim3(64, 2), 192, 0, stream>>>(adj2, curWT, p1, adjT, preWT, c1);

    // --- MLP2 ---
    k_gemm2<<<dim3(1024, 2), 72, 0, stream>>>(p1, c1, fc2_w0, fc2_b0, nullptr,
                                              Abuf, Bbuf, 144, 72);
    k_pair_mlp_mfma<<<dim3(64, 64), 256, 0, stream>>>(Abuf, Bbuf, w1fb + 576,
                                                      fc2_w2, fc2_b2,
                                                      (float2*)score2, adjout);
}